// Round 3
// baseline (40.188 us; speedup 1.0000x reference)
//
#include <hip/hip_runtime.h>
#include <math.h>

// Gaussian map generator: out[z,y,x] = sum_a amp[a] * exp(-c * |r_voxel - r_atom|^2)
// c = 1/(2 sigma^2), sigma = resolution/(sqrt(2) pi).  res=2 -> c~2.467; contributions
// vanish (<4e-18) beyond R = sqrt(40/c) ~ 4.03 A.
//
// Round 3: gather-by-slab.  Round 1-2 showed dur_us pinned at 27us regardless of the
// zeroing method -> the cost is the scatter kernel's 2.2M global fp32 atomics + the
// 2-node dependent graph.  New structure: 256 blocks, each owns a (z, y-half) 64x128
// fp32 plane in LDS; threads partition atoms, prune by slab range, accumulate <=9x9
// footprints with LDS atomics, then write the plane to global once, coalesced.
// No zero kernel, no global atomics, single graph node.

__global__ __launch_bounds__(256)
void gauss_slab(const float* __restrict__ coords,
                const float* __restrict__ amps,
                const float* __restrict__ pix,
                const int* __restrict__ resp,
                float* __restrict__ out,
                int n_atoms)
{
    const int NXg = 128, NYg = 128;
    const int YB = 64;                       // y-half per block
    __shared__ float plane[YB * NXg];        // 32 KiB

    const int z  = blockIdx.x >> 1;
    const int y0 = (blockIdx.x & 1) * YB;

    for (int i = threadIdx.x; i < YB * NXg; i += blockDim.x)
        plane[i] = 0.0f;

    // sigma = res/(sqrt(2) pi); c = 1/(2 sigma^2); cutoff R: exp(-40) ~ 4e-18
    const float res   = (float)resp[0];
    const float sigma = res / (sqrtf(2.0f) * 3.14159265358979323846f);
    const float c     = 1.0f / (2.0f * sigma * sigma);
    const float R     = sqrtf(40.0f / c);

    // affine grid from the actual pix_coords input (x fastest, then y, then z)
    const float ox = pix[0], oy = pix[1], oz = pix[2];
    const float sx = pix[3] - pix[0];
    const float sy = pix[NXg * 3 + 1] - pix[1];
    const float sz = pix[NXg * NYg * 3 + 2] - pix[2];

    __syncthreads();

    const float zf = oz + (float)z * sz;     // this block's z plane coordinate

    for (int a = threadIdx.x; a < n_atoms; a += blockDim.x) {
        const float cx = coords[3 * a + 0];
        const float cy = coords[3 * a + 1];
        const float cz = coords[3 * a + 2];

        const float dz = zf - cz;
        if (fabsf(dz) > R) continue;         // prunes ~82% of atoms per slice

        int iylo = max(y0,          (int)ceilf ((cy - R - oy) / sy));
        int iyhi = min(y0 + YB - 1, (int)floorf((cy + R - oy) / sy));
        if (iylo > iyhi) continue;

        int ixlo = max(0,           (int)ceilf ((cx - R - ox) / sx));
        int ixhi = min(NXg - 1,     (int)floorf((cx + R - ox) / sx));
        if (ixlo > ixhi) continue;

        const float wz = amps[a] * __expf(-c * dz * dz);

        // x-direction Gaussian table, fully unrolled -> stays in registers.
        // Entries past ixhi are the TRUE Gaussian values at those voxels, so
        // adding them (when ix < NXg) only improves accuracy; no predicate on ixhi.
        float exs[9];
#pragma unroll
        for (int i = 0; i < 9; ++i) {
            float d = ox + (float)(ixlo + i) * sx - cx;
            exs[i] = __expf(-c * d * d);
        }

        for (int iy = iylo; iy <= iyhi; ++iy) {
            float dy  = oy + (float)iy * sy - cy;
            float wyz = wz * __expf(-c * dy * dy);
            float* row = &plane[(iy - y0) * NXg];
#pragma unroll
            for (int i = 0; i < 9; ++i) {
                int ix = ixlo + i;
                if (ix < NXg) atomicAdd(&row[ix], wyz * exs[i]);
            }
        }
    }

    __syncthreads();

    // coalesced write-out: one plane, once
    float* dst = out + ((size_t)z * NYg + y0) * NXg;
    for (int i = threadIdx.x; i < YB * NXg; i += blockDim.x)
        dst[i] = plane[i];
}

extern "C" void kernel_launch(void* const* d_in, const int* in_sizes, int n_in,
                              void* d_out, int out_size, void* d_ws, size_t ws_size,
                              hipStream_t stream)
{
    const float* coords = (const float*)d_in[0];   // (3000, 3) f32
    const float* amps   = (const float*)d_in[1];   // (3000,)  f32
    const float* pix    = (const float*)d_in[2];   // (2097152, 3) f32
    const int*   resp   = (const int*)d_in[3];     // scalar int
    float* out = (float*)d_out;                    // (1,128,128,128) f32

    const int n_atoms = in_sizes[1];

    // 128 z-slices x 2 y-halves = 256 blocks; every voxel written exactly once,
    // so no zeroing pass is needed.
    gauss_slab<<<256, 256, 0, stream>>>(coords, amps, pix, resp, out, n_atoms);
}

// Round 4
// 15.207 us; speedup vs baseline: 2.6427x; 2.6427x over previous
//
#include <hip/hip_runtime.h>
#include <math.h>

// Gaussian map generator: out[z,y,x] = sum_a amp[a] * exp(-c * |r_voxel - r_atom|^2)
// c = 1/(2 sigma^2), sigma = resolution/(sqrt(2) pi).  res=2 -> c~2.467.
//
// Round 4: back to per-atom scatter (rounds 1-2: 27us; slab-gather round 3: 40us,
// killed by 1-block/CU occupancy + uncoalesced atom scans + divergence).
// Attack the atomic count: truncate at c*d^2 > 12 (neglected pair <= 16*e^-12 ~ 1e-4,
// integrated worst-voxel tail ~1e-5; threshold is 0.4125 -> 1000x margin).
// Footprint: 9^3=729 cube -> radius-2.2 sphere ~65 voxels => ~11x fewer atomics.
// Each task: one fused __expf(-c*d2) + one atomicAdd.  No LDS, no __syncthreads.

#define EXP_CUT 12.0f

__global__ __launch_bounds__(256)
void zero_out(float4* __restrict__ out, int n4)
{
    int i = blockIdx.x * blockDim.x + threadIdx.x;
    if (i < n4) out[i] = make_float4(0.f, 0.f, 0.f, 0.f);
}

__global__ __launch_bounds__(128)
void scatter_gauss(const float* __restrict__ coords,
                   const float* __restrict__ amps,
                   const float* __restrict__ pix,
                   const int* __restrict__ resp,
                   float* __restrict__ out)
{
    const int NXg = 128, NYg = 128, NZg = 128;

    const int a = blockIdx.x;
    const float cx = coords[a * 3 + 0];
    const float cy = coords[a * 3 + 1];
    const float cz = coords[a * 3 + 2];
    const float amp = amps[a];

    // sigma = res / (sqrt(2)*pi); c = 1/(2 sigma^2)
    const float res = (float)resp[0];
    const float sigma = res / (sqrtf(2.0f) * 3.14159265358979323846f);
    const float c = 1.0f / (2.0f * sigma * sigma);
    const float R = sqrtf(EXP_CUT / c);      // ~2.2 A for res=2

    // affine grid from the actual pix_coords input (x fastest, then y, then z)
    const float ox = pix[0], oy = pix[1], oz = pix[2];
    const float sx = pix[3] - pix[0];
    const float sy = pix[NXg * 3 + 1] - pix[1];
    const float sz = pix[NXg * NYg * 3 + 2] - pix[2];

    int ixlo = max(0,       (int)ceilf ((cx - R - ox) / sx));
    int ixhi = min(NXg - 1, (int)floorf((cx + R - ox) / sx));
    int iylo = max(0,       (int)ceilf ((cy - R - oy) / sy));
    int iyhi = min(NYg - 1, (int)floorf((cy + R - oy) / sy));
    int izlo = max(0,       (int)ceilf ((cz - R - oz) / sz));
    int izhi = min(NZg - 1, (int)floorf((cz + R - oz) / sz));

    const int nx = ixhi - ixlo + 1;
    const int ny = iyhi - iylo + 1;
    const int nz = izhi - izlo + 1;
    if (nx <= 0 || ny <= 0 || nz <= 0) return;  // atom outside grid (uniform branch)

    const int tasks = nx * ny * nz;              // typically ~5^3 = 125
    for (int t = threadIdx.x; t < tasks; t += blockDim.x) {
        int dx = t % nx;          // x fastest -> consecutive lanes, consecutive addrs
        int r  = t / nx;
        int dy = r % ny;
        int dz = r / ny;
        float fx = ox + (float)(ixlo + dx) * sx - cx;
        float fy = oy + (float)(iylo + dy) * sy - cy;
        float fz = oz + (float)(izlo + dz) * sz - cz;
        float e  = c * (fx * fx + fy * fy + fz * fz);
        if (e <= EXP_CUT) {       // spherical cut: skip cube corners (~48% of tasks)
            int idx = ((izlo + dz) * NYg + (iylo + dy)) * NXg + (ixlo + dx);
            atomicAdd(out + idx, amp * __expf(-e));
        }
    }
}

extern "C" void kernel_launch(void* const* d_in, const int* in_sizes, int n_in,
                              void* d_out, int out_size, void* d_ws, size_t ws_size,
                              hipStream_t stream)
{
    const float* coords = (const float*)d_in[0];   // (3000, 3) f32
    const float* amps   = (const float*)d_in[1];   // (3000,)  f32
    const float* pix    = (const float*)d_in[2];   // (2097152, 3) f32
    const int*   resp   = (const int*)d_in[3];     // scalar int
    float* out = (float*)d_out;                    // (1,128,128,128) f32

    const int n_atoms = in_sizes[1];

    // harness poisons d_out with 0xAA once and never re-poisons: zero every call.
    const int n4 = out_size / 4;                   // 2097152 floats -> 524288 float4
    zero_out<<<(n4 + 255) / 256, 256, 0, stream>>>((float4*)out, n4);
    scatter_gauss<<<n_atoms, 128, 0, stream>>>(coords, amps, pix, resp, out);
}